// Round 6
// baseline (407.020 us; speedup 1.0000x reference)
//
#include <hip/hip_runtime.h>
#include <hip/hip_bf16.h>
#include <stdint.h>

#define D_IN  4096
#define D_OUT 4096
#define MROWS 8192   // 2 * 4096 rows of x

using i32x4  = __attribute__((ext_vector_type(4)))  int;
using i32x16 = __attribute__((ext_vector_type(16))) int;

// -------- Kernel 1 (fused): RMSNorm -> i8 xn (per-row absmax scale)
//          AND w_q fp32 -> i8 (exact, values in {-1,0,1}) ------------------
__global__ __launch_bounds__(256) void prep_kernel(
    const float* __restrict__ x, const float* __restrict__ nw,
    signed char* __restrict__ xq, float* __restrict__ srow,
    const float* __restrict__ wq, signed char* __restrict__ wb) {
  const int b = blockIdx.x;
  const int t = threadIdx.x;

  if (b < MROWS) {
    const float4* xr  = (const float4*)(x + (size_t)b * D_IN);
    const float4* nw4 = (const float4*)nw;

    float4 p[4];
    float ss = 0.f, mx = 0.f;
#pragma unroll
    for (int i = 0; i < 4; ++i) {
      const float4 v = xr[i * 256 + t];
      const float4 w = nw4[i * 256 + t];
      ss += v.x * v.x + v.y * v.y + v.z * v.z + v.w * v.w;
      p[i].x = v.x * w.x; p[i].y = v.y * w.y;
      p[i].z = v.z * w.z; p[i].w = v.w * w.w;
      mx = fmaxf(mx, fmaxf(fmaxf(fabsf(p[i].x), fabsf(p[i].y)),
                           fmaxf(fabsf(p[i].z), fabsf(p[i].w))));
    }
#pragma unroll
    for (int off = 32; off > 0; off >>= 1) {
      ss += __shfl_down(ss, off, 64);
      mx = fmaxf(mx, __shfl_down(mx, off, 64));
    }

    __shared__ float rs[4], rm[4];
    if ((t & 63) == 0) { rs[t >> 6] = ss; rm[t >> 6] = mx; }
    __syncthreads();
    const float scale =
        rsqrtf((rs[0] + rs[1] + rs[2] + rs[3]) * (1.0f / D_IN) + 1e-6f);
    const float rowmax = fmaxf(fmaxf(rm[0], rm[1]), fmaxf(rm[2], rm[3])) * scale;
    const float s   = fmaxf(rowmax, 1e-20f) * (1.0f / 127.0f);
    const float f   = scale / s;   // = scale * 127 / rowmax
    if (t == 0) srow[b] = s;

    int* out = (int*)(xq + (size_t)b * D_IN);
#pragma unroll
    for (int i = 0; i < 4; ++i) {
      const int q0 = (int)rintf(p[i].x * f);
      const int q1 = (int)rintf(p[i].y * f);
      const int q2 = (int)rintf(p[i].z * f);
      const int q3 = (int)rintf(p[i].w * f);
      out[i * 256 + t] =
          (q0 & 0xFF) | ((q1 & 0xFF) << 8) | ((q2 & 0xFF) << 16) | (q3 << 24);
    }
  } else {
    const int cb = b - MROWS;
    const float4* w4 = (const float4*)wq;
    int* o = (int*)wb;
#pragma unroll
    for (int i = 0; i < 4; ++i) {
      const int idx = cb * 1024 + i * 256 + t;
      const float4 v = w4[idx];
      const int q0 = (int)v.x, q1 = (int)v.y, q2 = (int)v.z, q3 = (int)v.w;
      o[idx] = (q0 & 0xFF) | ((q1 & 0xFF) << 8) | ((q2 & 0xFF) << 16) | (q3 << 24);
    }
  }
}

// ---------------- Kernel 2: i8 GEMM (A: MxK, B: NxK i.e. B^T) -------------
// R6 = R5 skeleton (proven 130us: 256x256 tile, 8 waves 2Mx4N, BKB=64,
// 4-deep A+B LDS ring, 1 barrier/tile, reg-level fragment double-buffer)
// with two changes:
//   1) mfma_i32_32x32x32_i8 instead of 16x16x64: +11.7% rate (4404 vs 3944
//      TOPS) and HALF the MFMA issue count (16/wave/body). Same LDS bytes.
//      C/D (shape-determined, HW-verified): col=lane&31,
//      row=(reg&3)+8*(reg>>2)+4*(lane>>5), reg in [0,16).
//      A: m=lane&31, k=(lane>>5)*16+j (16B/lane); B mirrors on n.
//   2) 4-body unroll: all ring-slot indices compile-time (READF slots
//      1,2,3,0; STAGE slots 3,0,1,2) -> ds_read/stage addresses fold to
//      base+immediate, killing the ~500cyc/body VALU address math.
//
// LDS write swizzle UNCHANGED (proven 0 conflicts): 16B chunk (row, j) at
// slot j ^ ((row>>1)&3), applied on the global source, compensated in the
// read. New read pattern (32 rows x chunk (ks*2 + lane>>5)): compensation
// key (row>>1)&3 == (lane>>1)&3 (row base multiple of 32); bank audit:
// 8 x 16B bank-regions x exactly 8 lanes each -> conflict-free.
//
// Schedule invariant (R5, proven): at body-T start tiles <= T+1 landed,
// tile T+2 in flight. Body T: READF(T+1)->spare regs; STAGE(T+3);
// MFMA(T) on resident regs; vmcnt(4) [lands T+2]; barrier [publishes].
// STAGE(T+3) overwrites slot (T-1)&3, whose reads were consumed (lgkm
// drained) in body T-1, one barrier before. Never drains vmcnt to 0 in
// the main loop.
#define BM 256
#define BN 256
#define BKB 64                  // K bytes per tile
#define NKT (D_IN / BKB)        // 64 K-tiles
#define SLOT_BYTES (BM * BKB)   // 16 KB per ring slot per operand

#define WVM(n_) asm volatile("s_waitcnt vmcnt(" #n_ ")" ::: "memory")
#define BAR()   __builtin_amdgcn_s_barrier()

// Stage tile at byte offset k0_ (A+B, 2+2 global_load_lds) into slot ss_.
#define STAGE(k0_, ss_)                                                       \
  do {                                                                        \
    _Pragma("unroll") for (int _i = 0; _i < 2; ++_i)                          \
        __builtin_amdgcn_global_load_lds(                                     \
            (__attribute__((address_space(1))) void*)(A + aOff[_i] + (k0_)),  \
            (__attribute__((address_space(3))) void*)&sA[ss_][ldsOff[_i]],    \
            16, 0, 0);                                                        \
    _Pragma("unroll") for (int _i = 0; _i < 2; ++_i)                          \
        __builtin_amdgcn_global_load_lds(                                     \
            (__attribute__((address_space(1))) void*)(B + bOff[_i] + (k0_)),  \
            (__attribute__((address_space(3))) void*)&sB[ss_][ldsOff[_i]],    \
            16, 0, 0);                                                        \
  } while (0)

// Read one tile's fragments from ring slot rs_ (compile-time const):
// A: 4 m-tiles x 2 k-steps; B: 2 n-tiles x 2 k-steps. 12 x ds_read_b128.
#define READF(rs_, fa_, fb_)                                                  \
  do {                                                                        \
    _Pragma("unroll") for (int _i = 0; _i < 4; ++_i) {                        \
      fa_[_i * 2]     = *(const i32x4*)&sA[rs_][aoff0 + _i * 2048 + ck0];     \
      fa_[_i * 2 + 1] = *(const i32x4*)&sA[rs_][aoff0 + _i * 2048 + ck1];     \
    }                                                                         \
    _Pragma("unroll") for (int _j = 0; _j < 2; ++_j) {                        \
      fb_[_j * 2]     = *(const i32x4*)&sB[rs_][boff0 + _j * 2048 + ck0];     \
      fb_[_j * 2 + 1] = *(const i32x4*)&sB[rs_][boff0 + _j * 2048 + ck1];     \
    }                                                                         \
  } while (0)

// 16-MFMA cluster (ks outer so dependent acc pairs are 8 apart).
#define MFMA_C(fa_, fb_)                                                      \
  do {                                                                        \
    __builtin_amdgcn_s_setprio(1);                                            \
    _Pragma("unroll") for (int _ks = 0; _ks < 2; ++_ks)                       \
        _Pragma("unroll") for (int _i = 0; _i < 4; ++_i)                      \
            _Pragma("unroll") for (int _j = 0; _j < 2; ++_j)                  \
                acc[_i][_j] = __builtin_amdgcn_mfma_i32_32x32x32_i8(          \
                    fa_[_i * 2 + _ks], fb_[_j * 2 + _ks], acc[_i][_j],        \
                    0, 0, 0);                                                 \
    __builtin_amdgcn_s_setprio(0);                                            \
  } while (0)

// Body: prefetch next tile's frags (slot rs_), stage tile at kb+kofs_ into
// slot ss_, compute resident tile, counted wait, barrier.
#define BODY(rs_, fcA_, fcB_, fnA_, fnB_, kofs_, ss_)                         \
  do {                                                                        \
    READF(rs_, fnA_, fnB_);                                                   \
    STAGE(kb + (kofs_), ss_);                                                 \
    MFMA_C(fcA_, fcB_);                                                       \
    WVM(4);                                                                   \
    BAR();                                                                    \
  } while (0)

__global__ __launch_bounds__(512, 2) void gemm_kernel(
    const signed char* __restrict__ A,   // MROWS x D_IN i8
    const signed char* __restrict__ B,   // D_OUT x D_IN i8
    const float* __restrict__ srow,      // MROWS   (per-row dequant scale)
    const float* __restrict__ gamma,     // D_OUT
    float* __restrict__ C) {             // MROWS x D_OUT fp32
  __shared__ __align__(16) signed char sA[4][SLOT_BYTES];  // 64 KB
  __shared__ __align__(16) signed char sB[4][SLOT_BYTES];  // 64 KB

  const int tid  = threadIdx.x;
  const int lane = tid & 63;
  const int wv   = tid >> 6;     // 0..7
  const int wm   = wv >> 2;      // 0..1: 128-row half of the 256-row tile
  const int wn   = wv & 3;       // 0..3: 64-col quarter of the 256-col tile
  const int bn   = blockIdx.x;   // 0..15
  const int bm   = blockIdx.y;   // 0..31

  i32x16 acc[4][2];
#pragma unroll
  for (int i = 0; i < 4; ++i)
#pragma unroll
    for (int j = 0; j < 2; ++j) acc[i][j] = (i32x16){0};

  // Staging map (proven): per tile per operand 1024 chunks of 16B; chunk
  // c = i*512 + tid -> tile row r = c>>2, swizzled k-offset.
  size_t aOff[2], bOff[2];
  int ldsOff[2];
#pragma unroll
  for (int i = 0; i < 2; ++i) {
    const int c  = i * 512 + tid;
    const int r  = c >> 2;
    const int cc = ((c & 3) ^ ((r >> 1) & 3)) * 16;
    aOff[i] = (size_t)(bm * BM + r) * D_IN + cc;
    bOff[i] = (size_t)(bn * BN + r) * D_IN + cc;
    ldsOff[i] = (i * 512 + wv * 64) * 16;  // wave-uniform base; +lane*16 by HW
  }

  // Fragment read offsets for 32x32x32: row = base + (lane&31), logical
  // chunk = ks*2 + (lane>>5), phys = chunk ^ ((lane>>1)&3) (== (row>>1)&3
  // since row base is a multiple of 32).
  const int sxk   = (lane >> 1) & 3;
  const int ck0   = (((lane >> 5)) ^ sxk) * 16;
  const int ck1   = ((2 + (lane >> 5)) ^ sxk) * 16;
  const int aoff0 = (wm * 128 + (lane & 31)) * BKB;
  const int boff0 = (wn * 64  + (lane & 31)) * BKB;

  i32x4 f0a[8], f0b[4], f1a[8], f1b[4];

  // Prologue: stage tiles 0..2; vmcnt(4) lands tiles 0,1 (tile 2 in
  // flight); barrier; preload tile 0's fragments.
  int kb = 0;
  STAGE(0, 0); STAGE(BKB, 1); STAGE(2 * BKB, 2);
  WVM(4);
  BAR();
  READF(0, f0a, f0b);

  // Main loop: 4-body unroll -> all slot indices compile-time. Bodies
  // T..T+3 (T = 0,4,...,56): READF slots 1,2,3,0; STAGE slots 3,0,1,2.
#pragma unroll 1
  for (int T = 0; T < NKT - 4; T += 4) {
    BODY(1, f0a, f0b, f1a, f1b, 3 * BKB, 3);
    BODY(2, f1a, f1b, f0a, f0b, 4 * BKB, 0);
    BODY(3, f0a, f0b, f1a, f1b, 5 * BKB, 1);
    BODY(0, f1a, f1b, f0a, f0b, 6 * BKB, 2);
    kb += 4 * BKB;
  }
  // Tail: bodies 60..63 (kb = 60*BKB; stages issued through tile 62).
  BODY(1, f0a, f0b, f1a, f1b, 3 * BKB, 3);  // body 60, stages tile 63
  // Body 61: no stage; drain tile 63, publish.
  READF(2, f0a, f0b);
  MFMA_C(f1a, f1b);
  WVM(0);
  BAR();
  // Body 62: read tile 63 (slot 3), compute 62. No further DMA.
  READF(3, f1a, f1b);
  MFMA_C(f0a, f0b);
  // Body 63.
  MFMA_C(f1a, f1b);

  // Epilogue: y = acc * srow[row] * gamma[col].
  // 32x32 C/D: col = lane&31 (+j*32), row = rowb + i*32 + (rr&3)+8*(rr>>2).
  const int col0 = bn * BN + wn * 64 + (lane & 31);
  const int rowb = bm * BM + wm * 128 + ((lane >> 5) * 4);
  const float g0 = gamma[col0];
  const float g1 = gamma[col0 + 32];

#pragma unroll
  for (int i = 0; i < 4; ++i) {
#pragma unroll
    for (int rr = 0; rr < 16; ++rr) {
      const int row = rowb + i * 32 + (rr & 3) + 8 * (rr >> 2);
      const float sr = srow[row];
      C[(size_t)row * D_OUT + col0]      = (float)acc[i][0][rr] * sr * g0;
      C[(size_t)row * D_OUT + col0 + 32] = (float)acc[i][1][rr] * sr * g1;
    }
  }
}

#undef BODY
#undef MFMA_C
#undef READF
#undef STAGE
#undef WVM
#undef BAR

extern "C" void kernel_launch(void* const* d_in, const int* in_sizes, int n_in,
                              void* d_out, int out_size, void* d_ws, size_t ws_size,
                              hipStream_t stream) {
  const float* x     = (const float*)d_in[0];  // (2,4096,4096)
  const float* nw    = (const float*)d_in[1];  // (4096,)
  const float* wq    = (const float*)d_in[2];  // (4096,4096) {-1,0,1}
  const float* gamma = (const float*)d_in[3];  // (4096,)
  float* y = (float*)d_out;

  // Workspace: xq i8 (32 MB) | wb i8 (16 MB) | srow fp32 (32 KB)
  signed char* xq = (signed char*)d_ws;
  signed char* wb = xq + (size_t)MROWS * D_IN;
  float* srow = (float*)(wb + (size_t)D_OUT * D_IN);

  prep_kernel<<<MROWS + 4096, 256, 0, stream>>>(x, nw, xq, srow, wq, wb);

  gemm_kernel<<<dim3(D_OUT / BN, MROWS / BM), 512, 0, stream>>>(xq, wb, srow, gamma, y);
}

// Round 7
// 391.147 us; speedup vs baseline: 1.0406x; 1.0406x over previous
//
#include <hip/hip_runtime.h>
#include <hip/hip_bf16.h>
#include <stdint.h>

#define D_IN  4096
#define D_OUT 4096
#define MROWS 8192   // 2 * 4096 rows of x

using i32x4 = __attribute__((ext_vector_type(4))) int;

// -------- Kernel 1 (fused): RMSNorm -> i8 xn (per-row absmax scale)
//          AND w_q fp32 -> i8 (exact, values in {-1,0,1}) ------------------
__global__ __launch_bounds__(256) void prep_kernel(
    const float* __restrict__ x, const float* __restrict__ nw,
    signed char* __restrict__ xq, float* __restrict__ srow,
    const float* __restrict__ wq, signed char* __restrict__ wb) {
  const int b = blockIdx.x;
  const int t = threadIdx.x;

  if (b < MROWS) {
    const float4* xr  = (const float4*)(x + (size_t)b * D_IN);
    const float4* nw4 = (const float4*)nw;

    float4 p[4];
    float ss = 0.f, mx = 0.f;
#pragma unroll
    for (int i = 0; i < 4; ++i) {
      const float4 v = xr[i * 256 + t];
      const float4 w = nw4[i * 256 + t];
      ss += v.x * v.x + v.y * v.y + v.z * v.z + v.w * v.w;
      p[i].x = v.x * w.x; p[i].y = v.y * w.y;
      p[i].z = v.z * w.z; p[i].w = v.w * w.w;
      mx = fmaxf(mx, fmaxf(fmaxf(fabsf(p[i].x), fabsf(p[i].y)),
                           fmaxf(fabsf(p[i].z), fabsf(p[i].w))));
    }
#pragma unroll
    for (int off = 32; off > 0; off >>= 1) {
      ss += __shfl_down(ss, off, 64);
      mx = fmaxf(mx, __shfl_down(mx, off, 64));
    }

    __shared__ float rs[4], rm[4];
    if ((t & 63) == 0) { rs[t >> 6] = ss; rm[t >> 6] = mx; }
    __syncthreads();
    const float scale =
        rsqrtf((rs[0] + rs[1] + rs[2] + rs[3]) * (1.0f / D_IN) + 1e-6f);
    const float rowmax = fmaxf(fmaxf(rm[0], rm[1]), fmaxf(rm[2], rm[3])) * scale;
    const float s   = fmaxf(rowmax, 1e-20f) * (1.0f / 127.0f);
    const float f   = scale / s;   // = scale * 127 / rowmax
    if (t == 0) srow[b] = s;

    int* out = (int*)(xq + (size_t)b * D_IN);
#pragma unroll
    for (int i = 0; i < 4; ++i) {
      const int q0 = (int)rintf(p[i].x * f);
      const int q1 = (int)rintf(p[i].y * f);
      const int q2 = (int)rintf(p[i].z * f);
      const int q3 = (int)rintf(p[i].w * f);
      out[i * 256 + t] =
          (q0 & 0xFF) | ((q1 & 0xFF) << 8) | ((q2 & 0xFF) << 16) | (q3 << 24);
    }
  } else {
    const int cb = b - MROWS;
    const float4* w4 = (const float4*)wq;
    int* o = (int*)wb;
#pragma unroll
    for (int i = 0; i < 4; ++i) {
      const int idx = cb * 1024 + i * 256 + t;
      const float4 v = w4[idx];
      const int q0 = (int)v.x, q1 = (int)v.y, q2 = (int)v.z, q3 = (int)v.w;
      o[idx] = (q0 & 0xFF) | ((q1 & 0xFF) << 8) | ((q2 & 0xFF) << 16) | (q3 << 24);
    }
  }
}

// ---------------- Kernel 2: i8 GEMM (A: MxK, B: NxK i.e. B^T) -------------
// mfma_i32_16x16x64_i8: per lane A[m=lane&15][k=(lane>>4)*16 + j], j in [0,16).
// C/D layout (shape-determined): col=lane&15, row=(lane>>4)*4+reg.
// LDS XOR-swizzle (proven 0 conflicts with THIS 16x16 read pattern; the
// 32x32 pattern conflicted - R6 regression, do not revisit without a probe):
// 16B chunk (row, j) at slot j ^ ((row>>1)&3), applied on the global source,
// compensated in the ds_read address.
//
// R7 = R5 skeleton (proven 130us: 256x256 tile, 8 waves 2Mx4N, BKB=64,
// 4-deep A+B LDS ring, reg-level fragment double-buffer f0/f1) +
//   1) 4-body unroll, compile-time ring slots (R6-proven: VALUBusy 21->10%):
//      all ds_read/LDS-dest addresses fold to base + 16-bit immediate.
//   2) Barrier every 2 bodies (pair barriers). Safety: STAGE(T+3) overwrites
//      the slot read at body T-2; a pair-boundary barrier always separates
//      them. Publication: pair-end WVM(4)+BAR formally publishes tiles
//      <= B+2; mid-pair READF(T+1) additionally has >=1 full body (~1000cyc)
//      of margin over L2-warm DMA latency (~300cyc). Integer-exact absmax
//      is the corruption tripwire. Per-body WVM(4) kept (per-wave, free):
//      prefetch depth unchanged (never drains to 0 in the main loop).
//   Rationale: occupancy is register-capped at 2 waves/SIMD (acc in AGPRs,
//   ~128V+128A per wave), so the only overlap lever is letting the two
//   same-SIMD waves skew phases -> fewer lockstep points.
#define BM 256
#define BN 256
#define BKB 64                  // K bytes per tile == one MFMA k-step
#define NKT (D_IN / BKB)        // 64 K-tiles
#define SLOT_BYTES (BM * BKB)   // 16 KB per ring slot per operand

#define WVM(n_) asm volatile("s_waitcnt vmcnt(" #n_ ")" ::: "memory")
#define BAR()   __builtin_amdgcn_s_barrier()

// Stage tile at byte offset k0_ (A+B, 2+2 global_load_lds) into slot ss_.
#define STAGE(k0_, ss_)                                                       \
  do {                                                                        \
    _Pragma("unroll") for (int _i = 0; _i < 2; ++_i)                          \
        __builtin_amdgcn_global_load_lds(                                     \
            (__attribute__((address_space(1))) void*)(A + aOff[_i] + (k0_)),  \
            (__attribute__((address_space(3))) void*)&sA[ss_][ldsOff[_i]],    \
            16, 0, 0);                                                        \
    _Pragma("unroll") for (int _i = 0; _i < 2; ++_i)                          \
        __builtin_amdgcn_global_load_lds(                                     \
            (__attribute__((address_space(1))) void*)(B + bOff[_i] + (k0_)),  \
            (__attribute__((address_space(3))) void*)&sB[ss_][ldsOff[_i]],    \
            16, 0, 0);                                                        \
  } while (0)

// Read one tile's fragments from ring slot rs_ (compile-time const) into
// register arrays fa_/fb_: 8 A + 4 B ds_read_b128, all base+immediate.
#define READF(rs_, fa_, fb_)                                                  \
  do {                                                                        \
    _Pragma("unroll") for (int _i = 0; _i < 8; ++_i)                          \
        fa_[_i] = *(const i32x4*)&sA[rs_][aoff0 + _i * (16 * BKB)];           \
    _Pragma("unroll") for (int _j = 0; _j < 4; ++_j)                          \
        fb_[_j] = *(const i32x4*)&sB[rs_][boff0 + _j * (16 * BKB)];           \
  } while (0)

// 32-MFMA cluster on register fragments fa_/fb_.
#define MFMA_C(fa_, fb_)                                                      \
  do {                                                                        \
    __builtin_amdgcn_s_setprio(1);                                            \
    _Pragma("unroll") for (int _i = 0; _i < 8; ++_i)                          \
        _Pragma("unroll") for (int _j = 0; _j < 4; ++_j)                      \
            acc[_i][_j] = __builtin_amdgcn_mfma_i32_16x16x64_i8(              \
                fa_[_i], fb_[_j], acc[_i][_j], 0, 0, 0);                      \
    __builtin_amdgcn_s_setprio(0);                                            \
  } while (0)

// Body: prefetch next tile's frags (ring slot rs_) into fn*, stage tile at
// kb+kofs_ into slot ss_, compute resident tile from fc*, counted wait,
// optional barrier.
#define BODY(rs_, fcA_, fcB_, fnA_, fnB_, kofs_, ss_, BAR_)                   \
  do {                                                                        \
    READF(rs_, fnA_, fnB_);                                                   \
    STAGE(kb + (kofs_), ss_);                                                 \
    MFMA_C(fcA_, fcB_);                                                       \
    WVM(4);                                                                   \
    BAR_;                                                                     \
  } while (0)

__global__ __launch_bounds__(512, 2) void gemm_kernel(
    const signed char* __restrict__ A,   // MROWS x D_IN i8
    const signed char* __restrict__ B,   // D_OUT x D_IN i8
    const float* __restrict__ srow,      // MROWS   (per-row dequant scale)
    const float* __restrict__ gamma,     // D_OUT
    float* __restrict__ C) {             // MROWS x D_OUT fp32
  __shared__ __align__(16) signed char sA[4][SLOT_BYTES];  // 64 KB
  __shared__ __align__(16) signed char sB[4][SLOT_BYTES];  // 64 KB

  const int tid  = threadIdx.x;
  const int lane = tid & 63;
  const int wv   = tid >> 6;     // 0..7
  const int wm   = wv >> 2;      // 0..1: 128-row half of the 256-row tile
  const int wn   = wv & 3;       // 0..3: 64-col quarter of the 256-col tile
  const int bn   = blockIdx.x;   // 0..15
  const int bm   = blockIdx.y;   // 0..31

  i32x4 acc[8][4];
#pragma unroll
  for (int i = 0; i < 8; ++i)
#pragma unroll
    for (int j = 0; j < 4; ++j) acc[i][j] = (i32x4){0, 0, 0, 0};

  // Staging map (proven): per tile per operand 1024 chunks of 16B; chunk
  // c = i*512 + tid -> tile row r = c>>2, swizzled k-byte offset.
  size_t aOff[2], bOff[2];
  int ldsOff[2];
#pragma unroll
  for (int i = 0; i < 2; ++i) {
    const int c  = i * 512 + tid;
    const int r  = c >> 2;
    const int cc = ((c & 3) ^ ((r >> 1) & 3)) * 16;
    aOff[i] = (size_t)(bm * BM + r) * D_IN + cc;
    bOff[i] = (size_t)(bn * BN + r) * D_IN + cc;
    ldsOff[i] = (i * 512 + wv * 64) * 16;  // wave-uniform base; +lane*16 by HW
  }

  // Fragment read offsets (swizzle-compensated; row base is a multiple of
  // 16 so (row>>1)&3 == (lane>>1)&3).
  const int kk    = (((lane >> 4) ^ ((lane >> 1) & 3))) * 16;
  const int aoff0 = (wm * 128 + (lane & 15)) * BKB + kk;
  const int boff0 = (wn * 64  + (lane & 15)) * BKB + kk;

  i32x4 f0a[8], f0b[4], f1a[8], f1b[4];

  // Prologue: stage tiles 0..2; WVM(4) lands tiles 0,1 (tile 2 in flight);
  // barrier publishes; preload tile 0's fragments.
  STAGE(0, 0); STAGE(BKB, 1); STAGE(2 * BKB, 2);
  WVM(4);
  BAR();
  READF(0, f0a, f0b);

  // Main loop: 4-body unroll, compile-time slots. Bodies T..T+3
  // (T = 0,4,...,56): READF slots 1,2,3,0; STAGE slots 3,0,1,2.
  // Barriers only after odd bodies (pair barriers).
  int kb = 0;
#pragma unroll 1
  for (int T = 0; T < NKT - 4; T += 4) {
    BODY(1, f0a, f0b, f1a, f1b, 3 * BKB, 3, );       // body 4k
    BODY(2, f1a, f1b, f0a, f0b, 4 * BKB, 0, BAR()); // body 4k+1
    BODY(3, f0a, f0b, f1a, f1b, 5 * BKB, 1, );       // body 4k+2
    BODY(0, f1a, f1b, f0a, f0b, 6 * BKB, 2, BAR()); // body 4k+3
    kb += 4 * BKB;
  }
  // Tail: kb = 60*BKB; bodies 60..63 (per-body barriers, cheap).
  BODY(1, f0a, f0b, f1a, f1b, 3 * BKB, 3, BAR());   // body 60: stages tile 63
  // Body 61: READF(62)[slot 2], compute f1, drain tile 63, publish.
  READF(2, f0a, f0b);
  MFMA_C(f1a, f1b);
  WVM(0);
  BAR();
  // Body 62: READF(63)[slot 3], compute f0. No further DMA.
  READF(3, f1a, f1b);
  MFMA_C(f0a, f0b);
  // Body 63.
  MFMA_C(f1a, f1b);

  // Epilogue: y = acc * srow[row] * gamma[col]
  const int col0 = bn * BN + wn * 64 + (lane & 15);
  const int row0 = bm * BM + wm * 128 + ((lane >> 4) * 4);
  float g[4];
#pragma unroll
  for (int j = 0; j < 4; ++j) g[j] = gamma[col0 + j * 16];

#pragma unroll
  for (int i = 0; i < 8; ++i) {
#pragma unroll
    for (int r = 0; r < 4; ++r) {
      const int row = row0 + i * 16 + r;
      const float sr = srow[row];
#pragma unroll
      for (int j = 0; j < 4; ++j) {
        C[(size_t)row * D_OUT + col0 + j * 16] =
            (float)acc[i][j][r] * sr * g[j];
      }
    }
  }
}

#undef BODY
#undef MFMA_C
#undef READF
#undef STAGE
#undef WVM
#undef BAR

extern "C" void kernel_launch(void* const* d_in, const int* in_sizes, int n_in,
                              void* d_out, int out_size, void* d_ws, size_t ws_size,
                              hipStream_t stream) {
  const float* x     = (const float*)d_in[0];  // (2,4096,4096)
  const float* nw    = (const float*)d_in[1];  // (4096,)
  const float* wq    = (const float*)d_in[2];  // (4096,4096) {-1,0,1}
  const float* gamma = (const float*)d_in[3];  // (4096,)
  float* y = (float*)d_out;

  // Workspace: xq i8 (32 MB) | wb i8 (16 MB) | srow fp32 (32 KB)
  signed char* xq = (signed char*)d_ws;
  signed char* wb = xq + (size_t)MROWS * D_IN;
  float* srow = (float*)(wb + (size_t)D_OUT * D_IN);

  prep_kernel<<<MROWS + 4096, 256, 0, stream>>>(x, nw, xq, srow, wq, wb);

  gemm_kernel<<<dim3(D_OUT / BN, MROWS / BM), 512, 0, stream>>>(xq, wb, srow, gamma, y);
}

// Round 8
// 383.000 us; speedup vs baseline: 1.0627x; 1.0213x over previous
//
#include <hip/hip_runtime.h>
#include <hip/hip_bf16.h>
#include <stdint.h>

#define D_IN  4096
#define D_OUT 4096
#define MROWS 8192   // 2 * 4096 rows of x

using i32x4 = __attribute__((ext_vector_type(4))) int;

// -------- Kernel 1 (fused): RMSNorm -> i8 xn (per-row absmax scale)
//          AND w_q fp32 -> i8 (exact, values in {-1,0,1}) ------------------
// R8 rewrite of part 1: ONE ROW PER WAVE (was: one row per 256-thread
// block). No __syncthreads, no LDS roundtrip - the row reduce is 6
// shfl_xor steps. 16 float4/lane held in registers, loaded in 4 chunks to
// cap live VGPRs (~110 -> 16 waves/CU). Blocks [0, 2048): 4 rows per block
// (one per wave). Blocks [2048, 2048+4096): w_q conversion, unchanged.
// NOTE: the RMS sum is reassociated vs the old version -> absmax may move
// in the 4th decimal (benign); a gemm race would be O(0.1)+.
__global__ __launch_bounds__(256) void prep_kernel(
    const float* __restrict__ x, const float* __restrict__ nw,
    signed char* __restrict__ xq, float* __restrict__ srow,
    const float* __restrict__ wq, signed char* __restrict__ wb) {
  const int b = blockIdx.x;
  const int t = threadIdx.x;

  if (b < 2048) {
    const int lane = t & 63;
    const int row  = b * 4 + (t >> 6);
    const float4* xr  = (const float4*)(x + (size_t)row * D_IN);
    const float4* nw4 = (const float4*)nw;

    float4 p[16];
    float ss = 0.f, mx = 0.f;
#pragma unroll
    for (int c = 0; c < 4; ++c) {
      float4 v[4], w[4];
#pragma unroll
      for (int i = 0; i < 4; ++i) {
        v[i] = xr[(c * 4 + i) * 64 + lane];
        w[i] = nw4[(c * 4 + i) * 64 + lane];
      }
#pragma unroll
      for (int i = 0; i < 4; ++i) {
        ss += v[i].x * v[i].x + v[i].y * v[i].y +
              v[i].z * v[i].z + v[i].w * v[i].w;
        float4 pp;
        pp.x = v[i].x * w[i].x; pp.y = v[i].y * w[i].y;
        pp.z = v[i].z * w[i].z; pp.w = v[i].w * w[i].w;
        p[c * 4 + i] = pp;
        mx = fmaxf(mx, fmaxf(fmaxf(fabsf(pp.x), fabsf(pp.y)),
                             fmaxf(fabsf(pp.z), fabsf(pp.w))));
      }
    }
#pragma unroll
    for (int off = 1; off < 64; off <<= 1) {
      ss += __shfl_xor(ss, off, 64);
      mx = fmaxf(mx, __shfl_xor(mx, off, 64));
    }
    const float scale  = rsqrtf(ss * (1.0f / D_IN) + 1e-6f);
    const float rowmax = mx * scale;
    const float s = fmaxf(rowmax, 1e-20f) * (1.0f / 127.0f);
    const float f = scale / s;   // = scale * 127 / rowmax
    if (lane == 0) srow[row] = s;

    int* out = (int*)(xq + (size_t)row * D_IN);
#pragma unroll
    for (int i = 0; i < 16; ++i) {
      const int q0 = (int)rintf(p[i].x * f);
      const int q1 = (int)rintf(p[i].y * f);
      const int q2 = (int)rintf(p[i].z * f);
      const int q3 = (int)rintf(p[i].w * f);
      out[i * 64 + lane] =
          (q0 & 0xFF) | ((q1 & 0xFF) << 8) | ((q2 & 0xFF) << 16) | (q3 << 24);
    }
  } else {
    // ---- w_q conversion, fully coalesced (proven) ----
    const int cb = b - 2048;
    const float4* w4 = (const float4*)wq;
    int* o = (int*)wb;
#pragma unroll
    for (int i = 0; i < 4; ++i) {
      const int idx = cb * 1024 + i * 256 + t;
      const float4 v = w4[idx];
      const int q0 = (int)v.x, q1 = (int)v.y, q2 = (int)v.z, q3 = (int)v.w;
      o[idx] = (q0 & 0xFF) | ((q1 & 0xFF) << 8) | ((q2 & 0xFF) << 16) | (q3 << 24);
    }
  }
}

// ---------------- Kernel 2: i8 GEMM (A: MxK, B: NxK i.e. B^T) -------------
// mfma_i32_16x16x64_i8: per lane A[m=lane&15][k=(lane>>4)*16 + j], j in [0,16).
// C/D layout (shape-determined): col=lane&15, row=(lane>>4)*4+reg.
// LDS XOR-swizzle (proven 0 conflicts with the 16x16 read pattern; 32x32
// conflicted - R6): 16B chunk (row, j) at slot j ^ ((row>>1)&3), applied on
// the global source, compensated in the ds_read address.
//
// R8 = R5-EXACT skeleton (proven 130us: 256x256 tile, 8 waves 2Mx4N,
// BKB=64, 4-deep A+B LDS ring, 1 barrier/body, WVM(4) counted waits,
// reg-level fragment double-buffer f0/f1, runtime ring slots) + ONE change:
//   WAVE-ROLE STAGGER. Waves 0-3 (role A): {READF(T+1); STAGE; MFMA(T)}.
//   Waves 4-7 (role B): {MFMA(T); READF(T+1); STAGE}. Wave w sits on SIMD
//   w&3, so each SIMD hosts one A + one B wave -> while one drives the DS
//   port the other drives the MFMA pipe (R5's measured body = MFMA 1306cyc
//   + LDS 1130cyc SERIALIZED; anti-phase roles let them overlap).
//   Hazards identical to R5: both orders sit between the same barriers;
//   slot lifetimes, WVM counts, and barrier counts per path are unchanged.
#define BM 256
#define BN 256
#define BKB 64                  // K bytes per tile == one MFMA k-step
#define NKT (D_IN / BKB)        // 64 K-tiles
#define SLOT_BYTES (BM * BKB)   // 16 KB per ring slot per operand

#define WVM(n_) asm volatile("s_waitcnt vmcnt(" #n_ ")" ::: "memory")
#define BAR()   __builtin_amdgcn_s_barrier()

// Stage tile t_ (A+B, 2+2 global_load_lds, 16B/lane) into ring slot t_&3.
#define STAGE(t_)                                                             \
  do {                                                                        \
    _Pragma("unroll") for (int _i = 0; _i < 2; ++_i)                          \
        __builtin_amdgcn_global_load_lds(                                     \
            (__attribute__((address_space(1))) void*)(A + aOff[_i] +          \
                                                      (t_) * BKB),            \
            (__attribute__((address_space(3))) void*)&sA[(t_) & 3]            \
                                                       [ldsOff[_i]],          \
            16, 0, 0);                                                        \
    _Pragma("unroll") for (int _i = 0; _i < 2; ++_i)                          \
        __builtin_amdgcn_global_load_lds(                                     \
            (__attribute__((address_space(1))) void*)(B + bOff[_i] +          \
                                                      (t_) * BKB),            \
            (__attribute__((address_space(3))) void*)&sB[(t_) & 3]            \
                                                       [ldsOff[_i]],          \
            16, 0, 0);                                                        \
  } while (0)

// Read tile t_'s fragments from ring slot t_&3 into register arrays fa_/fb_.
#define READF(t_, fa_, fb_)                                                   \
  do {                                                                        \
    _Pragma("unroll") for (int _i = 0; _i < 8; ++_i)                          \
        fa_[_i] = *(const i32x4*)&sA[(t_) & 3][aoff0 + _i * (16 * BKB)];      \
    _Pragma("unroll") for (int _j = 0; _j < 4; ++_j)                          \
        fb_[_j] = *(const i32x4*)&sB[(t_) & 3][boff0 + _j * (16 * BKB)];      \
  } while (0)

// 32-MFMA cluster on register fragments fa_/fb_.
#define MFMA_C(fa_, fb_)                                                      \
  do {                                                                        \
    __builtin_amdgcn_s_setprio(1);                                            \
    _Pragma("unroll") for (int _i = 0; _i < 8; ++_i)                          \
        _Pragma("unroll") for (int _j = 0; _j < 4; ++_j)                      \
            acc[_i][_j] = __builtin_amdgcn_mfma_i32_16x16x64_i8(              \
                fa_[_i], fb_[_j], acc[_i][_j], 0, 0, 0);                      \
    __builtin_amdgcn_s_setprio(0);                                            \
  } while (0)

// Role-A body: prefetch next frags, stage, compute resident tile.
#define BODY_A(T_, fcA_, fcB_, fnA_, fnB_, STG_, WAIT_)                       \
  do {                                                                        \
    READF((T_) + 1, fnA_, fnB_);                                              \
    STG_;                                                                     \
    MFMA_C(fcA_, fcB_);                                                       \
    WAIT_;                                                                    \
    BAR();                                                                    \
  } while (0)

// Role-B body: compute first, then prefetch + stage (anti-phase).
#define BODY_B(T_, fcA_, fcB_, fnA_, fnB_, STG_, WAIT_)                       \
  do {                                                                        \
    MFMA_C(fcA_, fcB_);                                                       \
    READF((T_) + 1, fnA_, fnB_);                                              \
    STG_;                                                                     \
    WAIT_;                                                                    \
    BAR();                                                                    \
  } while (0)

__global__ __launch_bounds__(512, 2) void gemm_kernel(
    const signed char* __restrict__ A,   // MROWS x D_IN i8
    const signed char* __restrict__ B,   // D_OUT x D_IN i8
    const float* __restrict__ srow,      // MROWS   (per-row dequant scale)
    const float* __restrict__ gamma,     // D_OUT
    float* __restrict__ C) {             // MROWS x D_OUT fp32
  __shared__ __align__(16) signed char sA[4][SLOT_BYTES];  // 64 KB
  __shared__ __align__(16) signed char sB[4][SLOT_BYTES];  // 64 KB

  const int tid  = threadIdx.x;
  const int lane = tid & 63;
  const int wv   = tid >> 6;     // 0..7
  const int wm   = wv >> 2;      // 0..1: 128-row half of the 256-row tile
  const int wn   = wv & 3;       // 0..3: 64-col quarter of the 256-col tile
  const int bn   = blockIdx.x;   // 0..15
  const int bm   = blockIdx.y;   // 0..31

  i32x4 acc[8][4];
#pragma unroll
  for (int i = 0; i < 8; ++i)
#pragma unroll
    for (int j = 0; j < 4; ++j) acc[i][j] = (i32x4){0, 0, 0, 0};

  // Staging map (proven): per tile per operand 1024 chunks of 16B; chunk
  // c = i*512 + tid -> tile row r = c>>2, swizzled k-byte offset.
  size_t aOff[2], bOff[2];
  int ldsOff[2];
#pragma unroll
  for (int i = 0; i < 2; ++i) {
    const int c  = i * 512 + tid;
    const int r  = c >> 2;
    const int cc = ((c & 3) ^ ((r >> 1) & 3)) * 16;
    aOff[i] = (size_t)(bm * BM + r) * D_IN + cc;
    bOff[i] = (size_t)(bn * BN + r) * D_IN + cc;
    ldsOff[i] = (i * 512 + wv * 64) * 16;  // wave-uniform base; +lane*16 by HW
  }

  // Fragment read offsets (swizzle-compensated; row base is a multiple of
  // 16 so (row>>1)&3 == (lane>>1)&3).
  const int kk    = (((lane >> 4) ^ ((lane >> 1) & 3))) * 16;
  const int aoff0 = (wm * 128 + (lane & 15)) * BKB + kk;
  const int boff0 = (wn * 64  + (lane & 15)) * BKB + kk;

  i32x4 f0a[8], f0b[4], f1a[8], f1b[4];

  // Prologue: stage tiles 0..2; WVM(4) lands tiles 0,1 (tile 2 in flight);
  // barrier publishes; preload tile 0's fragments.
  STAGE(0); STAGE(1); STAGE(2);
  WVM(4);
  BAR();
  READF(0, f0a, f0b);

  // Main loop + per-role tails (bodies 0..61). Each path executes the same
  // number of barriers per iteration -> barrier-matched divergence.
  if (wm) {  // waves 4-7: role B (one per SIMD alongside a role-A wave)
#pragma unroll 1
    for (int T = 0; T < NKT - 4; T += 2) {
      BODY_B(T,     f0a, f0b, f1a, f1b, STAGE(T + 3), WVM(4));
      BODY_B(T + 1, f1a, f1b, f0a, f0b, STAGE(T + 4), WVM(4));
    }
    BODY_B(60, f0a, f0b, f1a, f1b, STAGE(63), WVM(4));
    BODY_B(61, f1a, f1b, f0a, f0b, ,          WVM(0));
  } else {   // waves 0-3: role A
#pragma unroll 1
    for (int T = 0; T < NKT - 4; T += 2) {
      BODY_A(T,     f0a, f0b, f1a, f1b, STAGE(T + 3), WVM(4));
      BODY_A(T + 1, f1a, f1b, f0a, f0b, STAGE(T + 4), WVM(4));
    }
    BODY_A(60, f0a, f0b, f1a, f1b, STAGE(63), WVM(4));
    BODY_A(61, f1a, f1b, f0a, f0b, ,          WVM(0));
  }
  // Shared tail: tile 63 landed (WVM(0)+BAR above in both paths).
  READF(63, f1a, f1b);
  MFMA_C(f0a, f0b);
  MFMA_C(f1a, f1b);

  // Epilogue: y = acc * srow[row] * gamma[col]
  const int col0 = bn * BN + wn * 64 + (lane & 15);
  const int row0 = bm * BM + wm * 128 + ((lane >> 4) * 4);
  float g[4];
#pragma unroll
  for (int j = 0; j < 4; ++j) g[j] = gamma[col0 + j * 16];

#pragma unroll
  for (int i = 0; i < 8; ++i) {
#pragma unroll
    for (int r = 0; r < 4; ++r) {
      const int row = row0 + i * 16 + r;
      const float sr = srow[row];
#pragma unroll
      for (int j = 0; j < 4; ++j) {
        C[(size_t)row * D_OUT + col0 + j * 16] =
            (float)acc[i][j][r] * sr * g[j];
      }
    }
  }
}

#undef BODY_A
#undef BODY_B
#undef MFMA_C
#undef READF
#undef STAGE
#undef WVM
#undef BAR

extern "C" void kernel_launch(void* const* d_in, const int* in_sizes, int n_in,
                              void* d_out, int out_size, void* d_ws, size_t ws_size,
                              hipStream_t stream) {
  const float* x     = (const float*)d_in[0];  // (2,4096,4096)
  const float* nw    = (const float*)d_in[1];  // (4096,)
  const float* wq    = (const float*)d_in[2];  // (4096,4096) {-1,0,1}
  const float* gamma = (const float*)d_in[3];  // (4096,)
  float* y = (float*)d_out;

  // Workspace: xq i8 (32 MB) | wb i8 (16 MB) | srow fp32 (32 KB)
  signed char* xq = (signed char*)d_ws;
  signed char* wb = xq + (size_t)MROWS * D_IN;
  float* srow = (float*)(wb + (size_t)D_OUT * D_IN);

  // 2048 rmsnorm blocks (1 row/wave) + 4096 w-conversion blocks
  prep_kernel<<<2048 + 4096, 256, 0, stream>>>(x, nw, xq, srow, wq, wb);

  gemm_kernel<<<dim3(D_OUT / BN, MROWS / BM), 512, 0, stream>>>(xq, wb, srow, gamma, y);
}